// Round 5
// baseline (295.120 us; speedup 1.0000x reference)
//
#include <hip/hip_runtime.h>
#include <math.h>

// Problem constants (B,S,D,H,F = 4,2048,512,8,2048)
constexpr int B = 4, S = 2048, D = 512, H = 8, HD = 64, F = 2048;
constexpr int M = B * S;                      // 8192 token rows
constexpr float C_QK = 0.125f * 1.44269504088896340736f;  // SCALE * log2(e)

typedef __bf16 bf16x8 __attribute__((ext_vector_type(8)));
typedef float  f32x4  __attribute__((ext_vector_type(4)));
typedef float  f32x16 __attribute__((ext_vector_type(16)));

static __device__ __forceinline__ short f2bf(float f) {
  return __builtin_bit_cast(short, (__bf16)f);   // RNE via fptrunc
}

static __device__ __forceinline__ void gload16(const void* g, void* l) {
  __builtin_amdgcn_global_load_lds(
      (const __attribute__((address_space(1))) unsigned int*)g,
      (__attribute__((address_space(3))) unsigned int*)l, 16, 0, 0);
}

// ---------------------------------------------------------------- prep (fused)
__global__ __launch_bounds__(256)
void prep_all(const float* __restrict__ x, short* __restrict__ xb,
              const float* __restrict__ w_qkv, short* __restrict__ wtq,
              const float* __restrict__ w_o,  short* __restrict__ wto,
              const float* __restrict__ w1,   short* __restrict__ wt1,
              const float* __restrict__ w2,   short* __restrict__ wt2) {
  __shared__ float tl[32][33];
  const int id = blockIdx.x;
  const int t = threadIdx.x;
  if (id < 4096) {
    int i = id * 256 + t;
    float4 v = ((const float4*)x)[i];
    ((short4*)xb)[i] = make_short4(f2bf(v.x), f2bf(v.y), f2bf(v.z), f2bf(v.w));
    return;
  }
  const float* in; short* out; int R, C, bx, by;
  if (id < 4864)      { int k = id - 4096; in = w_qkv; out = wtq; R = 512;  C = 1536; bx = k % 48; by = k / 48; }
  else if (id < 5120) { int k = id - 4864; in = w_o;   out = wto; R = 512;  C = 512;  bx = k % 16; by = k / 16; }
  else if (id < 6144) { int k = id - 5120; in = w1;    out = wt1; R = 512;  C = 2048; bx = k % 64; by = k / 64; }
  else                { int k = id - 6144; in = w2;    out = wt2; R = 2048; C = 512;  bx = k % 16; by = k / 16; }
  const int r0 = by * 32, c0 = bx * 32;
  const int tr = t >> 3, tc4 = (t & 7) * 4;
  float4 v = *(const float4*)&in[(size_t)(r0 + tr) * C + c0 + tc4];
  tl[tr][tc4] = v.x; tl[tr][tc4 + 1] = v.y; tl[tr][tc4 + 2] = v.z; tl[tr][tc4 + 3] = v.w;
  __syncthreads();
  short4 o = make_short4(f2bf(tl[tc4][tr]), f2bf(tl[tc4 + 1][tr]),
                         f2bf(tl[tc4 + 2][tr]), f2bf(tl[tc4 + 3][tr]));
  *(short4*)&out[(size_t)(c0 + tr) * R + r0 + tc4] = o;
}

// ---------------------------------------------------------------- GEMM (bf16 MFMA, 2-phase)
// C[M,N] = A[M,K] @ Wt[N,K]^T + bias. BM x BN tile, BK=64, double-buffered LDS,
// prefetch-next-then-compute, one barrier/step. XOR-swizzled stage/read pair.
// 4 waves in 2x2; wave tile = (BM/2) x (BN/2). EPI: 0 f32, 1 bf16, 2 QKV-split.
template<int BM, int BN, int GELU, int EPI>
__global__ __launch_bounds__(256)
void gemm_bf16(const short* __restrict__ A, const short* __restrict__ Wt,
               const float* __restrict__ bias,
               float* __restrict__ Cf, short* __restrict__ Cb,
               short* __restrict__ qsw, short* __restrict__ ksw,
               short* __restrict__ vsw, int K, int N) {
  constexpr int MI = BM / 32, NI = BN / 32;
  __shared__ short As[2][BM * 64] __attribute__((aligned(16)));
  __shared__ short Bs[2][BN * 64] __attribute__((aligned(16)));
  const int t = threadIdx.x;
  const int w = t >> 6, l = t & 63, g = l >> 4, r = l & 15;
  const int wm = w >> 1, wn = w & 1;
  const int m0 = blockIdx.y * BM, n0 = blockIdx.x * BN;

  auto stage = [&](int buf, int k0) {
#pragma unroll
    for (int i = 0; i < BM / 32; ++i) {
      int q = i * 256 + t;
      int row = q >> 3, sl = (q & 7) ^ (row & 7);
      gload16(A + (size_t)(m0 + row) * K + k0 + sl * 8, (char*)As[buf] + q * 16);
    }
#pragma unroll
    for (int i = 0; i < BN / 32; ++i) {
      int q = i * 256 + t;
      int row = q >> 3, sl = (q & 7) ^ (row & 7);
      gload16(Wt + (size_t)(n0 + row) * K + k0 + sl * 8, (char*)Bs[buf] + q * 16);
    }
  };

  f32x4 acc[MI][NI] = {};
  const int NS = K >> 6;
  stage(0, 0);
  __syncthreads();
  for (int st = 0; st < NS; ++st) {
    const int cur = st & 1;
    if (st + 1 < NS) stage(cur ^ 1, (st + 1) << 6);
    const short* Ac = As[cur];
    const short* Bc = Bs[cur];
#pragma unroll
    for (int kh = 0; kh < 2; ++kh) {
      const int cc = kh * 4 + g;              // 16B chunk index within 128B row
      bf16x8 aF[MI], bF[NI];
#pragma unroll
      for (int mi = 0; mi < MI; ++mi) {
        const int row = wm * (MI * 16) + mi * 16 + r;
        aF[mi] = *(const bf16x8*)(Ac + row * 64 + ((cc ^ (r & 7)) << 3));
      }
#pragma unroll
      for (int ni = 0; ni < NI; ++ni) {
        const int row = wn * (NI * 16) + ni * 16 + r;
        bF[ni] = *(const bf16x8*)(Bc + row * 64 + ((cc ^ (r & 7)) << 3));
      }
#pragma unroll
      for (int mi = 0; mi < MI; ++mi)
#pragma unroll
        for (int ni = 0; ni < NI; ++ni)
          acc[mi][ni] = __builtin_amdgcn_mfma_f32_16x16x32_bf16(aF[mi], bF[ni], acc[mi][ni], 0, 0, 0);
    }
    __syncthreads();                          // next-tile stage complete
  }

  // epilogue: C/D col = lane&15, row = (lane>>4)*4 + reg  [m89/m91]
#pragma unroll
  for (int mi = 0; mi < MI; ++mi) {
#pragma unroll
    for (int ni = 0; ni < NI; ++ni) {
      const int n  = n0 + wn * (NI * 16) + ni * 16 + r;
      const int mB = m0 + wm * (MI * 16) + mi * 16 + g * 4;
      float vals[4];
#pragma unroll
      for (int j = 0; j < 4; ++j) {
        float v = acc[mi][ni][j] + bias[n];
        if (GELU) v = 0.5f * v * (1.0f + erff(v * 0.70710678118654752f));
        vals[j] = v;
      }
      if (EPI == 0) {
#pragma unroll
        for (int j = 0; j < 4; ++j) Cf[(size_t)(mB + j) * N + n] = vals[j];
      } else if (EPI == 1) {
#pragma unroll
        for (int j = 0; j < 4; ++j) Cb[(size_t)(mB + j) * N + n] = f2bf(vals[j]);
      } else {
        const int b = mB >> 11, s = mB & 2047;
        if (n < 512) {                        // Q (pre-scaled): [b][h][s][d^swz]
          const int hh = n >> 6, d = n & 63;
          const size_t rb = (size_t)(b * 8 + hh) * 2048;
#pragma unroll
          for (int j = 0; j < 4; ++j)
            qsw[(rb + s + j) * 64 + (d ^ (((s + j) & 7) << 3))] = f2bf(vals[j] * C_QK);
        } else if (n < 1024) {                // K: same layout, unscaled
          const int hh = (n - 512) >> 6, d = (n - 512) & 63;
          const size_t rb = (size_t)(b * 8 + hh) * 2048;
#pragma unroll
          for (int j = 0; j < 4; ++j)
            ksw[(rb + s + j) * 64 + (d ^ (((s + j) & 7) << 3))] = f2bf(vals[j]);
        } else {                              // V: [b][h][d][s^swz]
          const int hh = (n - 1024) >> 6, d = (n - 1024) & 63;
          short4 pk = make_short4(f2bf(vals[0]), f2bf(vals[1]), f2bf(vals[2]), f2bf(vals[3]));
          *(short4*)&vsw[(size_t)((b * 8 + hh) * 64 + d) * 2048 + (s ^ ((d & 7) << 3))] = pk;
        }
      }
    }
  }
}

// ---------------------------------------------------------------- Attention v4 (split-KV)
// Grid (16, 32, 2): 4 waves x 32 q, KV half = 1024 keys (16 tiles of 64).
// Q frags direct from global (no Q LDS); K/V double-buffered (32 KB LDS).
// Writes normalized partial O (bf16) + L = m + log2(l) per q-row.
__global__ __launch_bounds__(256)
void attn_mfma(const short* __restrict__ qsw, const short* __restrict__ ksw,
               const short* __restrict__ vsw, short* __restrict__ Opart,
               float* __restrict__ Lpart) {
  __shared__ short Ks[2][64 * 64] __attribute__((aligned(16)));
  __shared__ short Vs[2][64 * 64] __attribute__((aligned(16)));
  const int t = threadIdx.x;
  const int w = t >> 6, l = t & 63;
  const int c = l & 31, hi = l >> 5;
  const int bh = blockIdx.y;
  const int q0 = blockIdx.x * 128;
  const int half = blockIdx.z;
  const int kbase = half * 1024;
  const short* qb = qsw + ((size_t)bh * 2048 + q0) * 64;
  const short* kb = ksw + (size_t)bh * 2048 * 64;
  const short* vb = vsw + (size_t)bh * 64 * 2048;

  auto stage_kv = [&](int buf, int kt) {
#pragma unroll
    for (int i = 0; i < 2; ++i) {
      int q = i * 256 + t;
      gload16(kb + (size_t)(kt + (q >> 3)) * 64 + (q & 7) * 8, (char*)Ks[buf] + q * 16);
    }
#pragma unroll
    for (int i = 0; i < 2; ++i) {
      int q = i * 256 + t;
      gload16(vb + (size_t)(q >> 3) * 2048 + kt + (q & 7) * 8, (char*)Vs[buf] + q * 16);
    }
  };

  // Q frags straight from (pre-swizzled, pre-scaled) global layout
  const int qrow = w * 32 + c;                // local q row; (q0+qrow)&7 == qrow&7
  const int swz = (c & 7) << 3;
  bf16x8 qf[4];
#pragma unroll
  for (int dc = 0; dc < 4; ++dc)
    qf[dc] = *(const bf16x8*)(qb + qrow * 64 + ((dc * 16 + hi * 8) ^ swz));

  stage_kv(0, kbase);
  __syncthreads();

  f32x16 o0 = {}, o1 = {};
  float m_run = -3e38f, l_run = 0.0f;

  for (int ti = 0; ti < 16; ++ti) {
    const int cur = ti & 1;
    if (ti < 15) stage_kv(cur ^ 1, kbase + (ti + 1) * 64);
    const short* Kc = Ks[cur];
    const short* Vc = Vs[cur];

    // S^T = K Q^T (scale pre-folded into Q)
    f32x16 s0 = {}, s1 = {};
    __builtin_amdgcn_s_setprio(1);
#pragma unroll
    for (int dc = 0; dc < 4; ++dc) {
      const int koff = (dc * 16 + hi * 8) ^ swz;
      bf16x8 kf0 = *(const bf16x8*)(Kc + c * 64 + koff);
      bf16x8 kf1 = *(const bf16x8*)(Kc + (32 + c) * 64 + koff);
      s0 = __builtin_amdgcn_mfma_f32_32x32x16_bf16(kf0, qf[dc], s0, 0, 0, 0);
      s1 = __builtin_amdgcn_mfma_f32_32x32x16_bf16(kf1, qf[dc], s1, 0, 0, 0);
    }
    __builtin_amdgcn_s_setprio(0);

    // in-lane softmax for q = w*32+c
    float tmax = -3e38f;
#pragma unroll
    for (int j = 0; j < 16; ++j) tmax = fmaxf(tmax, fmaxf(s0[j], s1[j]));
    tmax = fmaxf(tmax, __shfl_xor(tmax, 32, 64));
    if (__any(tmax - m_run > 8.0f)) {         // T13 defer-max (log2 domain)
      float mnew = fmaxf(m_run, tmax);
      float rs = __builtin_amdgcn_exp2f(m_run - mnew);
      m_run = mnew;
      l_run *= rs;
#pragma unroll
      for (int j = 0; j < 16; ++j) {
        float rj = __shfl(rs, (j & 3) + 8 * (j >> 2) + 4 * hi, 64);
        o0[j] *= rj; o1[j] *= rj;
      }
    }
    float rsum = 0.0f;
#pragma unroll
    for (int j = 0; j < 16; ++j) {
      s0[j] = __builtin_amdgcn_exp2f(s0[j] - m_run);
      s1[j] = __builtin_amdgcn_exp2f(s1[j] - m_run);
      rsum += s0[j] + s1[j];
    }
    rsum += __shfl_xor(rsum, 32, 64);
    l_run += rsum;

    // build PV A-frags (T12) and accumulate O
    __builtin_amdgcn_s_setprio(1);
#pragma unroll
    for (int kc = 0; kc < 4; ++kc) {
      const int jb = (kc & 1) * 8;
      int u0, u1, v0, v1;
      if (kc < 2) {
        asm("v_cvt_pk_bf16_f32 %0, %1, %2" : "=v"(u0) : "v"(s0[jb + 0]), "v"(s0[jb + 1]));
        asm("v_cvt_pk_bf16_f32 %0, %1, %2" : "=v"(u1) : "v"(s0[jb + 2]), "v"(s0[jb + 3]));
        asm("v_cvt_pk_bf16_f32 %0, %1, %2" : "=v"(v0) : "v"(s0[jb + 4]), "v"(s0[jb + 5]));
        asm("v_cvt_pk_bf16_f32 %0, %1, %2" : "=v"(v1) : "v"(s0[jb + 6]), "v"(s0[jb + 7]));
      } else {
        asm("v_cvt_pk_bf16_f32 %0, %1, %2" : "=v"(u0) : "v"(s1[jb + 0]), "v"(s1[jb + 1]));
        asm("v_cvt_pk_bf16_f32 %0, %1, %2" : "=v"(u1) : "v"(s1[jb + 2]), "v"(s1[jb + 3]));
        asm("v_cvt_pk_bf16_f32 %0, %1, %2" : "=v"(v0) : "v"(s1[jb + 4]), "v"(s1[jb + 5]));
        asm("v_cvt_pk_bf16_f32 %0, %1, %2" : "=v"(v1) : "v"(s1[jb + 6]), "v"(s1[jb + 7]));
      }
      asm volatile("v_permlane32_swap_b32 %0, %1" : "+v"(u0), "+v"(v0));
      asm volatile("v_permlane32_swap_b32 %0, %1" : "+v"(u1), "+v"(v1));
      int pw[4] = {u0, u1, v0, v1};
      bf16x8 pa = __builtin_bit_cast(bf16x8, *(int4*)pw);
      const int voff = (kc * 16 + hi * 8) ^ swz;
      bf16x8 vf0 = *(const bf16x8*)(Vc + c * 64 + voff);
      bf16x8 vf1 = *(const bf16x8*)(Vc + (32 + c) * 64 + voff);
      o0 = __builtin_amdgcn_mfma_f32_32x32x16_bf16(pa, vf0, o0, 0, 0, 0);
      o1 = __builtin_amdgcn_mfma_f32_32x32x16_bf16(pa, vf1, o1, 0, 0, 0);
    }
    __builtin_amdgcn_s_setprio(0);
    __syncthreads();
  }

  // write normalized partial O + L = m + log2(l)
  const size_t hrow = (size_t)half * (32 * 2048) + (size_t)bh * 2048;
  float inv = 1.0f / l_run;
  if (hi == 0)
    Lpart[hrow + q0 + w * 32 + c] = m_run + __builtin_log2f(l_run);
#pragma unroll
  for (int j = 0; j < 16; ++j) {
    const int q_rel = (j & 3) + 8 * (j >> 2) + 4 * hi;
    float invq = __shfl(inv, q_rel, 64);
    const size_t row = (hrow + q0 + w * 32 + q_rel) * 64;
    Opart[row + c]      = f2bf(o0[j] * invq);
    Opart[row + 32 + c] = f2bf(o1[j] * invq);
  }
}

// ---------------------------------------------------------------- attn combine
// out[bh,s,:] = (w0*O0 + w1*O1)/(w0+w1), wi = 2^(Li - Lmax). 8 d per thread.
__global__ __launch_bounds__(256)
void attn_combine(const short* __restrict__ Opart, const float* __restrict__ Lpart,
                  short* __restrict__ a_o) {
  const int idx = blockIdx.x * 256 + threadIdx.x;   // 524288 = 65536 rows x 8 chunks
  const int row = idx >> 3;                          // bh*2048 + s
  const int d8 = (idx & 7) * 8;
  const float L0 = Lpart[row], L1 = Lpart[65536 + row];
  const float mx = fmaxf(L0, L1);
  const float w0 = __builtin_amdgcn_exp2f(L0 - mx), w1 = __builtin_amdgcn_exp2f(L1 - mx);
  const float inv = 1.0f / (w0 + w1);
  bf16x8 a = *(const bf16x8*)(Opart + (size_t)row * 64 + d8);
  bf16x8 b = *(const bf16x8*)(Opart + ((size_t)65536 + row) * 64 + d8);
  bf16x8 res;
#pragma unroll
  for (int i = 0; i < 8; ++i)
    res[i] = (__bf16)((w0 * (float)a[i] + w1 * (float)b[i]) * inv);
  const int bh = row >> 11, s = row & 2047;
  const int bb = bh >> 3, hh = bh & 7;
  *(bf16x8*)(a_o + ((size_t)(bb * 2048 + s)) * 512 + hh * 64 + d8) = res;
}

// ---------------------------------------------------------------- Add + LayerNorm (fp32)
template<int WB>
__global__ __launch_bounds__(256)
void add_ln(const float* __restrict__ a, const float* __restrict__ res,
            const float* __restrict__ g_, const float* __restrict__ be,
            float* __restrict__ out, short* __restrict__ outb) {
  const int row = blockIdx.x;
  const int t = threadIdx.x;
  const size_t off = (size_t)row * D;
  float x0 = a[off + t] + res[off + t];
  float x1 = a[off + t + 256] + res[off + t + 256];
  float sum = x0 + x1;
  float sq  = x0 * x0 + x1 * x1;
#pragma unroll
  for (int o2 = 32; o2 > 0; o2 >>= 1) {
    sum += __shfl_down(sum, o2);
    sq  += __shfl_down(sq, o2);
  }
  __shared__ float ssum[4], ssq[4];
  const int wid = t >> 6;
  if ((t & 63) == 0) { ssum[wid] = sum; ssq[wid] = sq; }
  __syncthreads();
  if (t == 0) {
    ssum[0] = ssum[0] + ssum[1] + ssum[2] + ssum[3];
    ssq[0]  = ssq[0] + ssq[1] + ssq[2] + ssq[3];
  }
  __syncthreads();
  float mu   = ssum[0] * (1.0f / D);
  float var  = ssq[0] * (1.0f / D) - mu * mu;
  float rstd = rsqrtf(var + 1e-5f);
  float y0 = (x0 - mu) * rstd * g_[t] + be[t];
  float y1 = (x1 - mu) * rstd * g_[t + 256] + be[t + 256];
  out[off + t] = y0;
  out[off + t + 256] = y1;
  if (WB) {
    outb[off + t] = f2bf(y0);
    outb[off + t + 256] = f2bf(y1);
  }
}

// ---------------------------------------------------------------- launch
extern "C" void kernel_launch(void* const* d_in, const int* in_sizes, int n_in,
                              void* d_out, int out_size, void* d_ws, size_t ws_size,
                              hipStream_t stream) {
  const float* x     = (const float*)d_in[0];
  const float* w_qkv = (const float*)d_in[1];
  const float* b_qkv = (const float*)d_in[2];
  const float* w_o   = (const float*)d_in[3];
  const float* b_o   = (const float*)d_in[4];
  const float* w1    = (const float*)d_in[5];
  const float* b1    = (const float*)d_in[6];
  const float* w2    = (const float*)d_in[7];
  const float* b2    = (const float*)d_in[8];
  const float* g1    = (const float*)d_in[9];
  const float* be1   = (const float*)d_in[10];
  const float* g2    = (const float*)d_in[11];
  const float* be2   = (const float*)d_in[12];
  float* out = (float*)d_out;
  (void)in_sizes; (void)n_in; (void)out_size; (void)ws_size;

  const size_t MD = (size_t)M * 512;
  short* q_sw = (short*)d_ws;           // [B][H][S][64] swz (pre-scaled)
  short* k_sw = q_sw + MD;
  short* v_sw = k_sw + MD;              // [B][H][64][S] swz
  short* a_o  = v_sw + MD;              // attn out [M][512]
  short* h    = q_sw;                   // FFN hidden overlays q/k/v/a_o (dead)
  short* xb   = a_o + MD;
  short* ln1b = xb;                     // ln1 bf16 overlays xb (dead after GEMM1)
  short* wtq  = xb + MD;
  short* wto  = wtq + (size_t)1536 * 512;
  short* wt1  = wto + (size_t)512 * 512;
  short* wt2  = wt1 + (size_t)512 * 2048;
  float* buf  = (float*)(wt2 + (size_t)2048 * 512);
  float* ln1  = buf + MD;
  short* Opart = (short*)(ln1 + MD);    // [2][32][2048][64] bf16 = 16.8 MB
  float* Lpart = (float*)(Opart + (size_t)2 * 32 * 2048 * 64);  // [2][65536] f32

  prep_all<<<7168, 256, 0, stream>>>(x, xb, w_qkv, wtq, w_o, wto, w1, wt1, w2, wt2);

  gemm_bf16<128, 64, 0, 2><<<dim3(24, 64), 256, 0, stream>>>(
      xb, wtq, b_qkv, nullptr, nullptr, q_sw, k_sw, v_sw, 512, 1536);
  attn_mfma<<<dim3(16, 32, 2), 256, 0, stream>>>(q_sw, k_sw, v_sw, Opart, Lpart);
  attn_combine<<<2048, 256, 0, stream>>>(Opart, Lpart, a_o);
  gemm_bf16<64, 64, 0, 0><<<dim3(8, 128), 256, 0, stream>>>(
      a_o, wto, b_o, buf, nullptr, nullptr, nullptr, nullptr, 512, 512);
  add_ln<1><<<M, 256, 0, stream>>>(buf, x, g1, be1, ln1, ln1b);
  gemm_bf16<128, 64, 1, 1><<<dim3(32, 64), 256, 0, stream>>>(
      ln1b, wt1, b1, nullptr, h, nullptr, nullptr, nullptr, 512, 2048);
  gemm_bf16<64, 64, 0, 0><<<dim3(8, 128), 256, 0, stream>>>(
      h, wt2, b2, buf, nullptr, nullptr, nullptr, nullptr, 2048, 512);
  add_ln<0><<<M, 256, 0, stream>>>(buf, ln1, g2, be2, out, nullptr);
}

// Round 6
// 285.064 us; speedup vs baseline: 1.0353x; 1.0353x over previous
//
#include <hip/hip_runtime.h>
#include <math.h>

// Problem constants (B,S,D,H,F = 4,2048,512,8,2048)
constexpr int B = 4, S = 2048, D = 512, H = 8, HD = 64, F = 2048;
constexpr int M = B * S;                      // 8192 token rows
constexpr float C_QK = 0.125f * 1.44269504088896340736f;  // SCALE * log2(e)

typedef __bf16 bf16x8 __attribute__((ext_vector_type(8)));
typedef float  f32x4  __attribute__((ext_vector_type(4)));
typedef float  f32x16 __attribute__((ext_vector_type(16)));

static __device__ __forceinline__ short f2bf(float f) {
  return __builtin_bit_cast(short, (__bf16)f);   // RNE via fptrunc
}

static __device__ __forceinline__ void gload16(const void* g, void* l) {
  __builtin_amdgcn_global_load_lds(
      (const __attribute__((address_space(1))) unsigned int*)g,
      (__attribute__((address_space(3))) unsigned int*)l, 16, 0, 0);
}

// ---------------------------------------------------------------- prep (fused)
__global__ __launch_bounds__(256)
void prep_all(const float* __restrict__ x, short* __restrict__ xb,
              const float* __restrict__ w_qkv, short* __restrict__ wtq,
              const float* __restrict__ w_o,  short* __restrict__ wto,
              const float* __restrict__ w1,   short* __restrict__ wt1,
              const float* __restrict__ w2,   short* __restrict__ wt2) {
  __shared__ float tl[32][33];
  const int id = blockIdx.x;
  const int t = threadIdx.x;
  if (id < 4096) {
    int i = id * 256 + t;
    float4 v = ((const float4*)x)[i];
    ((short4*)xb)[i] = make_short4(f2bf(v.x), f2bf(v.y), f2bf(v.z), f2bf(v.w));
    return;
  }
  const float* in; short* out; int R, C, bx, by;
  if (id < 4864)      { int k = id - 4096; in = w_qkv; out = wtq; R = 512;  C = 1536; bx = k % 48; by = k / 48; }
  else if (id < 5120) { int k = id - 4864; in = w_o;   out = wto; R = 512;  C = 512;  bx = k % 16; by = k / 16; }
  else if (id < 6144) { int k = id - 5120; in = w1;    out = wt1; R = 512;  C = 2048; bx = k % 64; by = k / 64; }
  else                { int k = id - 6144; in = w2;    out = wt2; R = 2048; C = 512;  bx = k % 16; by = k / 16; }
  const int r0 = by * 32, c0 = bx * 32;
  const int tr = t >> 3, tc4 = (t & 7) * 4;
  float4 v = *(const float4*)&in[(size_t)(r0 + tr) * C + c0 + tc4];
  tl[tr][tc4] = v.x; tl[tr][tc4 + 1] = v.y; tl[tr][tc4 + 2] = v.z; tl[tr][tc4 + 3] = v.w;
  __syncthreads();
  short4 o = make_short4(f2bf(tl[tc4][tr]), f2bf(tl[tc4 + 1][tr]),
                         f2bf(tl[tc4 + 2][tr]), f2bf(tl[tc4 + 3][tr]));
  *(short4*)&out[(size_t)(c0 + tr) * R + r0 + tc4] = o;
}

// ---------------------------------------------------------------- GEMM (bf16 MFMA, 2-phase)
// C[M,N] = A[M,K] @ Wt[N,K]^T + bias. BM x BN tile, BK=64, double-buffered LDS,
// prefetch-next-then-compute, one barrier/step. XOR-swizzled stage/read pair.
// 4 waves in 2x2; wave tile = (BM/2) x (BN/2). EPI: 0 f32, 1 bf16, 2 QKV-split.
template<int BM, int BN, int GELU, int EPI>
__global__ __launch_bounds__(256)
void gemm_bf16(const short* __restrict__ A, const short* __restrict__ Wt,
               const float* __restrict__ bias,
               float* __restrict__ Cf, short* __restrict__ Cb,
               short* __restrict__ qsw, short* __restrict__ ksw,
               short* __restrict__ vsw, int K, int N) {
  constexpr int MI = BM / 32, NI = BN / 32;
  __shared__ short As[2][BM * 64] __attribute__((aligned(16)));
  __shared__ short Bs[2][BN * 64] __attribute__((aligned(16)));
  const int t = threadIdx.x;
  const int w = t >> 6, l = t & 63, g = l >> 4, r = l & 15;
  const int wm = w >> 1, wn = w & 1;
  const int m0 = blockIdx.y * BM, n0 = blockIdx.x * BN;

  auto stage = [&](int buf, int k0) {
#pragma unroll
    for (int i = 0; i < BM / 32; ++i) {
      int q = i * 256 + t;
      int row = q >> 3, sl = (q & 7) ^ (row & 7);
      gload16(A + (size_t)(m0 + row) * K + k0 + sl * 8, (char*)As[buf] + q * 16);
    }
#pragma unroll
    for (int i = 0; i < BN / 32; ++i) {
      int q = i * 256 + t;
      int row = q >> 3, sl = (q & 7) ^ (row & 7);
      gload16(Wt + (size_t)(n0 + row) * K + k0 + sl * 8, (char*)Bs[buf] + q * 16);
    }
  };

  f32x4 acc[MI][NI] = {};
  const int NS = K >> 6;
  stage(0, 0);
  __syncthreads();
  for (int st = 0; st < NS; ++st) {
    const int cur = st & 1;
    if (st + 1 < NS) stage(cur ^ 1, (st + 1) << 6);
    const short* Ac = As[cur];
    const short* Bc = Bs[cur];
#pragma unroll
    for (int kh = 0; kh < 2; ++kh) {
      const int cc = kh * 4 + g;              // 16B chunk index within 128B row
      bf16x8 aF[MI], bF[NI];
#pragma unroll
      for (int mi = 0; mi < MI; ++mi) {
        const int row = wm * (MI * 16) + mi * 16 + r;
        aF[mi] = *(const bf16x8*)(Ac + row * 64 + ((cc ^ (r & 7)) << 3));
      }
#pragma unroll
      for (int ni = 0; ni < NI; ++ni) {
        const int row = wn * (NI * 16) + ni * 16 + r;
        bF[ni] = *(const bf16x8*)(Bc + row * 64 + ((cc ^ (r & 7)) << 3));
      }
#pragma unroll
      for (int mi = 0; mi < MI; ++mi)
#pragma unroll
        for (int ni = 0; ni < NI; ++ni)
          acc[mi][ni] = __builtin_amdgcn_mfma_f32_16x16x32_bf16(aF[mi], bF[ni], acc[mi][ni], 0, 0, 0);
    }
    __syncthreads();                          // next-tile stage complete
  }

  // epilogue: C/D col = lane&15, row = (lane>>4)*4 + reg  [m89/m91]
#pragma unroll
  for (int mi = 0; mi < MI; ++mi) {
#pragma unroll
    for (int ni = 0; ni < NI; ++ni) {
      const int n  = n0 + wn * (NI * 16) + ni * 16 + r;
      const int mB = m0 + wm * (MI * 16) + mi * 16 + g * 4;
      float vals[4];
#pragma unroll
      for (int j = 0; j < 4; ++j) {
        float v = acc[mi][ni][j] + bias[n];
        if (GELU) v = 0.5f * v * (1.0f + erff(v * 0.70710678118654752f));
        vals[j] = v;
      }
      if (EPI == 0) {
#pragma unroll
        for (int j = 0; j < 4; ++j) Cf[(size_t)(mB + j) * N + n] = vals[j];
      } else if (EPI == 1) {
#pragma unroll
        for (int j = 0; j < 4; ++j) Cb[(size_t)(mB + j) * N + n] = f2bf(vals[j]);
      } else {
        const int b = mB >> 11, s = mB & 2047;
        if (n < 512) {                        // Q (pre-scaled): [b][h][s][d^swz]
          const int hh = n >> 6, d = n & 63;
          const size_t rb = (size_t)(b * 8 + hh) * 2048;
#pragma unroll
          for (int j = 0; j < 4; ++j)
            qsw[(rb + s + j) * 64 + (d ^ (((s + j) & 7) << 3))] = f2bf(vals[j] * C_QK);
        } else if (n < 1024) {                // K: same layout, unscaled
          const int hh = (n - 512) >> 6, d = (n - 512) & 63;
          const size_t rb = (size_t)(b * 8 + hh) * 2048;
#pragma unroll
          for (int j = 0; j < 4; ++j)
            ksw[(rb + s + j) * 64 + (d ^ (((s + j) & 7) << 3))] = f2bf(vals[j]);
        } else {                              // V: [b][h][d][s^swz]
          const int hh = (n - 1024) >> 6, d = (n - 1024) & 63;
          short4 pk = make_short4(f2bf(vals[0]), f2bf(vals[1]), f2bf(vals[2]), f2bf(vals[3]));
          *(short4*)&vsw[(size_t)((b * 8 + hh) * 64 + d) * 2048 + (s ^ ((d & 7) << 3))] = pk;
        }
      }
    }
  }
}

// ---------------------------------------------------------------- Attention v5 (split-KV, reg-diet)
// Grid (16, 32, 2): 4 waves x 32 q, KV half = 1024 keys. Single-buffered K/V
// (16 KB LDS). 64-key tile processed as two 32-key sub-tiles so only ONE
// f32x16 S-block is live (-16 regs). __launch_bounds__(256,4) forces <=128
// unified VGPRs -> 4 waves/SIMD; 4 blocks/CU -> 16 waves/CU.
__global__ __launch_bounds__(256, 4)
void attn_mfma(const short* __restrict__ qsw, const short* __restrict__ ksw,
               const short* __restrict__ vsw, short* __restrict__ Opart,
               float* __restrict__ Lpart) {
  __shared__ short Ks[64 * 64] __attribute__((aligned(16)));
  __shared__ short Vs[64 * 64] __attribute__((aligned(16)));
  const int t = threadIdx.x;
  const int w = t >> 6, l = t & 63;
  const int c = l & 31, hi = l >> 5;
  const int bh = blockIdx.y;
  const int q0 = blockIdx.x * 128;
  const int kbase = blockIdx.z * 1024;
  const short* qb = qsw + ((size_t)bh * 2048 + q0) * 64;
  const short* kb = ksw + (size_t)bh * 2048 * 64;
  const short* vb = vsw + (size_t)bh * 64 * 2048;

  // Q frags straight from (pre-swizzled, pre-scaled) global layout
  const int qrow = w * 32 + c;
  const int swz = (c & 7) << 3;
  bf16x8 qf[4];
#pragma unroll
  for (int dc = 0; dc < 4; ++dc)
    qf[dc] = *(const bf16x8*)(qb + qrow * 64 + ((dc * 16 + hi * 8) ^ swz));

  f32x16 o0 = {}, o1 = {};
  float m_run = -3e38f, l_run = 0.0f;

  for (int ti = 0; ti < 16; ++ti) {
    const int kt = kbase + ti * 64;
    __syncthreads();                          // prior tile's readers done
#pragma unroll
    for (int i = 0; i < 2; ++i) {             // K tile [64 keys][64 d]
      int q = i * 256 + t;
      gload16(kb + (size_t)(kt + (q >> 3)) * 64 + (q & 7) * 8, (char*)Ks + q * 16);
    }
#pragma unroll
    for (int i = 0; i < 2; ++i) {             // V tile [64 d][64 s]
      int q = i * 256 + t;
      gload16(vb + (size_t)(q >> 3) * 2048 + kt + (q & 7) * 8, (char*)Vs + q * 16);
    }
    __syncthreads();                          // stage visible

#pragma unroll
    for (int h2 = 0; h2 < 2; ++h2) {          // two 32-key sub-tiles
      // S^T = K Q^T (scale pre-folded into Q); one f32x16 live
      f32x16 s = {};
      __builtin_amdgcn_s_setprio(1);
#pragma unroll
      for (int dc = 0; dc < 4; ++dc) {
        const int koff = (dc * 16 + hi * 8) ^ swz;
        bf16x8 kf = *(const bf16x8*)(Ks + (h2 * 32 + c) * 64 + koff);
        s = __builtin_amdgcn_mfma_f32_32x32x16_bf16(kf, qf[dc], s, 0, 0, 0);
      }
      __builtin_amdgcn_s_setprio(0);

      // in-lane online softmax for q = w*32+c (16 values)
      float tmax = -3e38f;
#pragma unroll
      for (int j = 0; j < 16; ++j) tmax = fmaxf(tmax, s[j]);
      tmax = fmaxf(tmax, __shfl_xor(tmax, 32, 64));
      if (__any(tmax - m_run > 8.0f)) {       // T13 defer-max (log2 domain)
        float mnew = fmaxf(m_run, tmax);
        float rs = __builtin_amdgcn_exp2f(m_run - mnew);
        m_run = mnew;
        l_run *= rs;
#pragma unroll
        for (int j = 0; j < 16; ++j) {        // per-row rescale: q_rel(j,hi)
          float rj = __shfl(rs, (j & 3) + 8 * (j >> 2) + 4 * hi, 64);
          o0[j] *= rj; o1[j] *= rj;
        }
      }
      float rsum = 0.0f;
#pragma unroll
      for (int j = 0; j < 16; ++j) {
        s[j] = __builtin_amdgcn_exp2f(s[j] - m_run);
        rsum += s[j];
      }
      rsum += __shfl_xor(rsum, 32, 64);
      l_run += rsum;

      // build PV A-frags (T12) and accumulate O
      __builtin_amdgcn_s_setprio(1);
#pragma unroll
      for (int kc = 0; kc < 2; ++kc) {        // 2 x k16 within the 32-key half
        const int jb = kc * 8;
        int u0, u1, v0, v1;
        asm("v_cvt_pk_bf16_f32 %0, %1, %2" : "=v"(u0) : "v"(s[jb + 0]), "v"(s[jb + 1]));
        asm("v_cvt_pk_bf16_f32 %0, %1, %2" : "=v"(u1) : "v"(s[jb + 2]), "v"(s[jb + 3]));
        asm("v_cvt_pk_bf16_f32 %0, %1, %2" : "=v"(v0) : "v"(s[jb + 4]), "v"(s[jb + 5]));
        asm("v_cvt_pk_bf16_f32 %0, %1, %2" : "=v"(v1) : "v"(s[jb + 6]), "v"(s[jb + 7]));
        asm volatile("v_permlane32_swap_b32 %0, %1" : "+v"(u0), "+v"(v0));
        asm volatile("v_permlane32_swap_b32 %0, %1" : "+v"(u1), "+v"(v1));
        int pw[4] = {u0, u1, v0, v1};
        bf16x8 pa = __builtin_bit_cast(bf16x8, *(int4*)pw);
        const int voff = ((h2 * 32 + kc * 16 + hi * 8)) ^ swz;
        bf16x8 vf0 = *(const bf16x8*)(Vs + c * 64 + voff);
        bf16x8 vf1 = *(const bf16x8*)(Vs + (32 + c) * 64 + voff);
        o0 = __builtin_amdgcn_mfma_f32_32x32x16_bf16(pa, vf0, o0, 0, 0, 0);
        o1 = __builtin_amdgcn_mfma_f32_32x32x16_bf16(pa, vf1, o1, 0, 0, 0);
      }
      __builtin_amdgcn_s_setprio(0);
    }
  }

  // write normalized partial O + L = m + log2(l)
  const size_t hrow = (size_t)blockIdx.z * (32 * 2048) + (size_t)bh * 2048;
  float inv = 1.0f / l_run;
  if (hi == 0)
    Lpart[hrow + q0 + w * 32 + c] = m_run + __builtin_log2f(l_run);
#pragma unroll
  for (int j = 0; j < 16; ++j) {
    const int q_rel = (j & 3) + 8 * (j >> 2) + 4 * hi;
    float invq = __shfl(inv, q_rel, 64);
    const size_t row = (hrow + q0 + w * 32 + q_rel) * 64;
    Opart[row + c]      = f2bf(o0[j] * invq);
    Opart[row + 32 + c] = f2bf(o1[j] * invq);
  }
}

// ---------------------------------------------------------------- attn combine
__global__ __launch_bounds__(256)
void attn_combine(const short* __restrict__ Opart, const float* __restrict__ Lpart,
                  short* __restrict__ a_o) {
  const int idx = blockIdx.x * 256 + threadIdx.x;   // 524288 = 65536 rows x 8 chunks
  const int row = idx >> 3;                          // bh*2048 + s
  const int d8 = (idx & 7) * 8;
  const float L0 = Lpart[row], L1 = Lpart[65536 + row];
  const float mx = fmaxf(L0, L1);
  const float w0 = __builtin_amdgcn_exp2f(L0 - mx), w1 = __builtin_amdgcn_exp2f(L1 - mx);
  const float inv = 1.0f / (w0 + w1);
  bf16x8 a = *(const bf16x8*)(Opart + (size_t)row * 64 + d8);
  bf16x8 b = *(const bf16x8*)(Opart + ((size_t)65536 + row) * 64 + d8);
  bf16x8 res;
#pragma unroll
  for (int i = 0; i < 8; ++i)
    res[i] = (__bf16)((w0 * (float)a[i] + w1 * (float)b[i]) * inv);
  const int bh = row >> 11, s = row & 2047;
  const int bb = bh >> 3, hh = bh & 7;
  *(bf16x8*)(a_o + ((size_t)(bb * 2048 + s)) * 512 + hh * 64 + d8) = res;
}

// ---------------------------------------------------------------- Add + LayerNorm (fp32)
template<int WB>
__global__ __launch_bounds__(256)
void add_ln(const float* __restrict__ a, const float* __restrict__ res,
            const float* __restrict__ g_, const float* __restrict__ be,
            float* __restrict__ out, short* __restrict__ outb) {
  const int row = blockIdx.x;
  const int t = threadIdx.x;
  const size_t off = (size_t)row * D;
  float x0 = a[off + t] + res[off + t];
  float x1 = a[off + t + 256] + res[off + t + 256];
  float sum = x0 + x1;
  float sq  = x0 * x0 + x1 * x1;
#pragma unroll
  for (int o2 = 32; o2 > 0; o2 >>= 1) {
    sum += __shfl_down(sum, o2);
    sq  += __shfl_down(sq, o2);
  }
  __shared__ float ssum[4], ssq[4];
  const int wid = t >> 6;
  if ((t & 63) == 0) { ssum[wid] = sum; ssq[wid] = sq; }
  __syncthreads();
  if (t == 0) {
    ssum[0] = ssum[0] + ssum[1] + ssum[2] + ssum[3];
    ssq[0]  = ssq[0] + ssq[1] + ssq[2] + ssq[3];
  }
  __syncthreads();
  float mu   = ssum[0] * (1.0f / D);
  float var  = ssq[0] * (1.0f / D) - mu * mu;
  float rstd = rsqrtf(var + 1e-5f);
  float y0 = (x0 - mu) * rstd * g_[t] + be[t];
  float y1 = (x1 - mu) * rstd * g_[t + 256] + be[t + 256];
  out[off + t] = y0;
  out[off + t + 256] = y1;
  if (WB) {
    outb[off + t] = f2bf(y0);
    outb[off + t + 256] = f2bf(y1);
  }
}

// ---------------------------------------------------------------- launch
extern "C" void kernel_launch(void* const* d_in, const int* in_sizes, int n_in,
                              void* d_out, int out_size, void* d_ws, size_t ws_size,
                              hipStream_t stream) {
  const float* x     = (const float*)d_in[0];
  const float* w_qkv = (const float*)d_in[1];
  const float* b_qkv = (const float*)d_in[2];
  const float* w_o   = (const float*)d_in[3];
  const float* b_o   = (const float*)d_in[4];
  const float* w1    = (const float*)d_in[5];
  const float* b1    = (const float*)d_in[6];
  const float* w2    = (const float*)d_in[7];
  const float* b2    = (const float*)d_in[8];
  const float* g1    = (const float*)d_in[9];
  const float* be1   = (const float*)d_in[10];
  const float* g2    = (const float*)d_in[11];
  const float* be2   = (const float*)d_in[12];
  float* out = (float*)d_out;
  (void)in_sizes; (void)n_in; (void)out_size; (void)ws_size;

  const size_t MD = (size_t)M * 512;
  short* q_sw = (short*)d_ws;           // [B][H][S][64] swz (pre-scaled)
  short* k_sw = q_sw + MD;
  short* v_sw = k_sw + MD;              // [B][H][64][S] swz
  short* a_o  = v_sw + MD;              // attn out [M][512]
  short* h    = q_sw;                   // FFN hidden overlays q/k/v/a_o (dead)
  short* xb   = a_o + MD;
  short* ln1b = xb;                     // ln1 bf16 overlays xb (dead after GEMM1)
  short* wtq  = xb + MD;
  short* wto  = wtq + (size_t)1536 * 512;
  short* wt1  = wto + (size_t)512 * 512;
  short* wt2  = wt1 + (size_t)512 * 2048;
  float* buf  = (float*)(wt2 + (size_t)2048 * 512);
  float* ln1  = buf + MD;
  short* Opart = (short*)(ln1 + MD);    // [2][32][2048][64] bf16 = 16.8 MB
  float* Lpart = (float*)(Opart + (size_t)2 * 32 * 2048 * 64);  // [2][65536] f32

  prep_all<<<7168, 256, 0, stream>>>(x, xb, w_qkv, wtq, w_o, wto, w1, wt1, w2, wt2);

  gemm_bf16<128, 64, 0, 2><<<dim3(24, 64), 256, 0, stream>>>(
      xb, wtq, b_qkv, nullptr, nullptr, q_sw, k_sw, v_sw, 512, 1536);
  attn_mfma<<<dim3(16, 32, 2), 256, 0, stream>>>(q_sw, k_sw, v_sw, Opart, Lpart);
  attn_combine<<<2048, 256, 0, stream>>>(Opart, Lpart, a_o);
  gemm_bf16<64, 64, 0, 0><<<dim3(8, 128), 256, 0, stream>>>(
      a_o, wto, b_o, buf, nullptr, nullptr, nullptr, nullptr, 512, 512);
  add_ln<1><<<M, 256, 0, stream>>>(buf, x, g1, be1, ln1, ln1b);
  gemm_bf16<128, 64, 1, 1><<<dim3(32, 64), 256, 0, stream>>>(
      ln1b, wt1, b1, nullptr, h, nullptr, nullptr, nullptr, 512, 2048);
  gemm_bf16<64, 64, 0, 0><<<dim3(8, 128), 256, 0, stream>>>(
      h, wt2, b2, buf, nullptr, nullptr, nullptr, nullptr, 2048, 512);
  add_ln<0><<<M, 256, 0, stream>>>(buf, ln1, g2, be2, out, nullptr);
}